// Round 1
// baseline (312.139 us; speedup 1.0000x reference)
//
#include <hip/hip_runtime.h>

#define BB 32
#define NN 2048
#define HH 512
#define MASK_NEG 1e30f

static __device__ __forceinline__ float dot4(float4 a, float4 b) {
    return a.x * b.x + a.y * b.y + a.z * b.z + a.w * b.w;
}

// Kernel 1: scores[b,n] = adj ? K[b,n]·wk : -1e30   (softmax is shift-invariant,
// so the per-row constant Q·wq + b_att is dropped — it cancels exactly)
__global__ void k_scores(const float* __restrict__ K,
                         const float* __restrict__ w_att,
                         const int* __restrict__ adj,
                         float* __restrict__ scores) {
    int wave = (blockIdx.x * blockDim.x + threadIdx.x) >> 6;
    int lane = threadIdx.x & 63;
    if (wave >= BB * NN) return;
    const float* wk = w_att + HH;
    size_t base = (size_t)wave * HH;
    float4 k0 = *(const float4*)(K + base + lane * 4);
    float4 k1 = *(const float4*)(K + base + 256 + lane * 4);
    float4 a0 = *(const float4*)(wk + lane * 4);
    float4 a1 = *(const float4*)(wk + 256 + lane * 4);
    float s = dot4(k0, a0) + dot4(k1, a1);
#pragma unroll
    for (int off = 32; off > 0; off >>= 1) s += __shfl_down(s, off, 64);
    if (lane == 0) scores[wave] = adj[wave] ? s : -MASK_NEG;
}

// Kernel 2: in-place softmax over n for each b. 32 blocks x 256 threads, 8 elems/thread.
__global__ void k_softmax(float* __restrict__ attn) {
    __shared__ float red[4];
    int b = blockIdx.x;
    int t = threadIdx.x;
    float v[8];
    float m = -INFINITY;
#pragma unroll
    for (int i = 0; i < 8; i++) {
        v[i] = attn[b * NN + t * 8 + i];
        m = fmaxf(m, v[i]);
    }
#pragma unroll
    for (int off = 32; off > 0; off >>= 1) m = fmaxf(m, __shfl_xor(m, off, 64));
    if ((t & 63) == 0) red[t >> 6] = m;
    __syncthreads();
    float m4 = fmaxf(fmaxf(red[0], red[1]), fmaxf(red[2], red[3]));
    float sum = 0.0f;
#pragma unroll
    for (int i = 0; i < 8; i++) {
        v[i] = expf(v[i] - m4);
        sum += v[i];
    }
#pragma unroll
    for (int off = 32; off > 0; off >>= 1) sum += __shfl_xor(sum, off, 64);
    __syncthreads();
    if ((t & 63) == 0) red[t >> 6] = sum;
    __syncthreads();
    float inv = 1.0f / (red[0] + red[1] + red[2] + red[3]);
#pragma unroll
    for (int i = 0; i < 8; i++) attn[b * NN + t * 8 + i] = v[i] * inv;
}

// Kernel 3: u0[b,h] = sum_n attn*sm*V ; u1[b,h] = sum_n attn*(1-sm)*V
// grid = B*16 blocks (128-row chunks), 256 threads; thread covers 4 h, 64 rows.
__global__ void k_wsum(const float* __restrict__ V,
                       const float* __restrict__ attn,
                       const int* __restrict__ s_mask,
                       float* __restrict__ u0,
                       float* __restrict__ u1) {
    int b = blockIdx.x >> 4;
    int chunk = blockIdx.x & 15;
    int n0 = chunk * 128;
    int t = threadIdx.x;
    int h4 = (t & 127) * 4;
    int half = t >> 7;  // 0 or 1 -> rows [0,64) or [64,128) of the chunk
    __shared__ float w0s[128], w1s[128];
    if (t < 128) {
        float w = attn[b * NN + n0 + t];
        int sm = s_mask[b * NN + n0 + t];
        w0s[t] = sm ? w : 0.0f;
        w1s[t] = sm ? 0.0f : w;
    }
    __syncthreads();
    float4 a0 = {0, 0, 0, 0}, a1 = {0, 0, 0, 0};
    const float* Vb = V + ((size_t)(b * NN + n0 + half * 64)) * HH + h4;
#pragma unroll 4
    for (int i = 0; i < 64; i++) {
        float4 x = *(const float4*)(Vb + (size_t)i * HH);
        float w0 = w0s[half * 64 + i];
        float w1 = w1s[half * 64 + i];
        a0.x += w0 * x.x; a0.y += w0 * x.y; a0.z += w0 * x.z; a0.w += w0 * x.w;
        a1.x += w1 * x.x; a1.y += w1 * x.y; a1.z += w1 * x.z; a1.w += w1 * x.w;
    }
    float* p0 = u0 + b * HH + h4;
    float* p1 = u1 + b * HH + h4;
    atomicAdd(p0 + 0, a0.x); atomicAdd(p0 + 1, a0.y);
    atomicAdd(p0 + 2, a0.z); atomicAdd(p0 + 3, a0.w);
    atomicAdd(p1 + 0, a1.x); atomicAdd(p1 + 1, a1.y);
    atomicAdd(p1 + 2, a1.z); atomicAdd(p1 + 3, a1.w);
}

// Kernel 4: attn_sum[b,o] = Wr0[o,:]·u0[b,:] + Wr1[o,:]·u1[b,:] + Wri[o,:]·Q[b,:]
// one wave per (b,o)
__global__ void k_out(const float* __restrict__ Q,
                      const float* __restrict__ Wr0,
                      const float* __restrict__ Wr1,
                      const float* __restrict__ Wri,
                      const float* __restrict__ u0,
                      const float* __restrict__ u1,
                      float* __restrict__ out) {
    int wave = (blockIdx.x * blockDim.x + threadIdx.x) >> 6;
    int lane = threadIdx.x & 63;
    if (wave >= BB * HH) return;
    int b = wave >> 9;
    int o = wave & 511;
    const float* q = Q + b * HH;
    const float* a = u0 + b * HH;
    const float* c = u1 + b * HH;
    const float* r0 = Wr0 + (size_t)o * HH;
    const float* r1 = Wr1 + (size_t)o * HH;
    const float* ri = Wri + (size_t)o * HH;
    float s = 0.0f;
#pragma unroll
    for (int part = 0; part < 2; part++) {
        int h = part * 256 + lane * 4;
        s += dot4(*(const float4*)(r0 + h), *(const float4*)(a + h));
        s += dot4(*(const float4*)(r1 + h), *(const float4*)(c + h));
        s += dot4(*(const float4*)(ri + h), *(const float4*)(q + h));
    }
#pragma unroll
    for (int off = 32; off > 0; off >>= 1) s += __shfl_down(s, off, 64);
    if (lane == 0) out[wave] = s;
}

extern "C" void kernel_launch(void* const* d_in, const int* in_sizes, int n_in,
                              void* d_out, int out_size, void* d_ws, size_t ws_size,
                              hipStream_t stream) {
    const float* Q = (const float*)d_in[0];
    const float* K = (const float*)d_in[1];
    const float* V = (const float*)d_in[2];
    const int* adj = (const int*)d_in[3];
    const int* s_mask = (const int*)d_in[4];
    const float* w_att = (const float*)d_in[5];
    // d_in[6] = b_att: unused — softmax is invariant to per-row constants.
    const float* Wr0 = (const float*)d_in[7];
    const float* Wr1 = (const float*)d_in[8];
    const float* Wri = (const float*)d_in[9];

    float* out = (float*)d_out;
    float* attn = out;              // B*N = 65536 floats (output 0)
    float* attn_sum = out + BB * NN;  // B*H = 16384 floats (output 1)
    float* u0 = (float*)d_ws;
    float* u1 = u0 + BB * HH;

    hipMemsetAsync(d_ws, 0, 2 * BB * HH * sizeof(float), stream);
    k_scores<<<(BB * NN) / 4, 256, 0, stream>>>(K, w_att, adj, attn);
    k_softmax<<<BB, 256, 0, stream>>>(attn);
    k_wsum<<<BB * 16, 256, 0, stream>>>(V, attn, s_mask, u0, u1);
    k_out<<<(BB * HH) / 4, 256, 0, stream>>>(Q, Wr0, Wr1, Wri, u0, u1, attn_sum);
}